// Round 10
// baseline (312.306 us; speedup 1.0000x reference)
//
#include <hip/hip_runtime.h>
#include <stdint.h>
#include <math.h>

typedef unsigned short u16;
typedef __bf16 bf16x8 __attribute__((ext_vector_type(8)));
typedef __bf16 bf16x2 __attribute__((ext_vector_type(2)));
typedef unsigned short u16x8 __attribute__((ext_vector_type(8)));
typedef float f32x4 __attribute__((ext_vector_type(4)));

#define DEVI __device__ __forceinline__

constexpr int B_ = 8, N_ = 1024, D_ = 768, H_ = 12, DH_ = 64, DF_ = 1536;
// log2(e)/8: folded into Q so QK^T scores are in base-2 domain
constexpr float QSCALE = 0.18033688011112042f;
constexpr float THR2 = 11.5415603f;   // defer-max threshold 8 * log2(e)

// float -> bf16 bits, round-to-nearest-even (finite inputs only)
DEVI u16 f2bu(float f) {
  unsigned x = __builtin_bit_cast(unsigned, f);
  x += 0x7FFFu + ((x >> 16) & 1u);
  return (u16)(x >> 16);
}
DEVI float b2f(u16 u) { return __builtin_bit_cast(float, (unsigned)u << 16); }

DEVI bf16x8 ld_frag(const u16* p) {
  return __builtin_bit_cast(bf16x8, *(const u16x8*)p);
}

DEVI void gload_lds16(const u16* g, u16* l) {
  __builtin_amdgcn_global_load_lds(
      (const __attribute__((address_space(1))) void*)g,
      (__attribute__((address_space(3))) void*)l, 16, 0, 0);
}

// ---------------------------------------------------------------------------
// compact: per batch b, list of valid key tokens (node_mask==1), pad with 0.
// nkparr[b] = padded count (mult of 64); nkparr[8+b] = exact count.
__global__ __launch_bounds__(1024)
void compact(const int* __restrict__ nm, int* __restrict__ idx,
             int* __restrict__ nkparr) {
  const int b = blockIdx.x, t = threadIdx.x;
  const int wave = t >> 6, lane = t & 63;
  const bool valid = nm[b * N_ + t] != 0;
  const unsigned long long ball = __ballot(valid);
  const int pre = (int)__popcll(ball & ((1ull << lane) - 1ull));
  __shared__ int wsum[16];
  if (lane == 0) wsum[wave] = (int)__popcll(ball);
  __syncthreads();
  int base = 0;
#pragma unroll
  for (int i = 0; i < 16; ++i) base += (i < wave) ? wsum[i] : 0;
  int total = 0;
#pragma unroll
  for (int i = 0; i < 16; ++i) total += wsum[i];
  if (valid) idx[b * N_ + base + pre] = t;
  if (t < N_ - total) idx[b * N_ + total + t] = 0;   // pad -> token 0
  if (t == 0) { nkparr[b] = (total + 63) & ~63; nkparr[8 + b] = total; }
}

// ---------------------------------------------------------------------------
// prep_all: ONE launch = compacted-key mask packing (blocks 0..2047, gathers
// rel rows via idx, early-exits chunks beyond nkp) + all seven fp32->bf16
// converts (blocks 2048..12799).
// mp[((b*H+h)*(N/16) + st)*N + q], bit j = "head h masked at slot st*16+j".
struct CvtArgs {
  const float* src[7];
  u16* dst[7];
  int n4[7];
  int start[8];
};
__global__ __launch_bounds__(256)
void prep_all(CvtArgs a, const float* __restrict__ rel,
              const int* __restrict__ idx, const int* __restrict__ nkparr,
              u16* __restrict__ mp) {
  const int gb0 = blockIdx.x;
  const int t = threadIdx.x;
  if (gb0 < 2048) {
    const int b = gb0 >> 8, q0 = ((gb0 >> 2) & 63) * 16, k0 = (gb0 & 3) * 256;
    const int nkp = nkparr[b], nk = nkparr[8 + b];
    if (k0 >= nkp) return;
    const int s = k0 + t;                 // key slot
    const int tok = idx[b * N_ + s];      // gathered token (0 for pad)
    const bool vs = (s < nk);
    __shared__ u16 w12[16][256];
    const float th = 1e-4f;
#pragma unroll 1
    for (int it = 0; it < 16; ++it) {
      unsigned bits;
      if (!vs) {
        bits = 0xFFFu;
      } else {
        const size_t ridx = (((size_t)(b << 10) + q0 + it) << 10) + tok;
        const float2* rp = (const float2*)(rel + ridx * 10);
        float2 a0 = rp[0], a1 = rp[1], a2 = rp[2], a3 = rp[3], a4 = rp[4];
        bits  = (a0.x < th ? 1u : 0u)   | (a0.y < th ? 2u : 0u)
              | (a1.x < th ? 4u : 0u)   | (a1.y < th ? 8u : 0u)
              | (a2.x < th ? 16u : 0u)  | (a2.y < th ? 32u : 0u)
              | (a3.x < th ? 64u : 0u)  | (a3.y < th ? 128u : 0u)
              | (a4.x < th ? 256u : 0u) | (a4.y < th ? 512u : 0u);
      }
      w12[it][t ^ ((it & 7) << 1)] = (u16)bits;
    }
    __syncthreads();
    const int ql = t & 15, kt = t >> 4;
    unsigned wv[16];
#pragma unroll
    for (int j2 = 0; j2 < 8; ++j2) {
      const int e = (kt * 16 + j2 * 2) ^ ((ql & 7) << 1);
      wv[j2 * 2] = w12[ql][e];
      wv[j2 * 2 + 1] = w12[ql][e + 1];
    }
#pragma unroll
    for (int h = 0; h < 12; ++h) {
      unsigned word = 0;
#pragma unroll
      for (int j = 0; j < 16; ++j) word |= ((wv[j] >> h) & 1u) << j;
      mp[(((size_t)(b * H_ + h)) * (N_ / 16) + (k0 >> 4) + kt) * N_ + q0 + ql] = (u16)word;
    }
  } else {
    int j = 0;
    while (gb0 >= a.start[j + 1]) ++j;
    const int i = (gb0 - a.start[j]) * 256 + t;
    if (i >= a.n4[j]) return;
    float4 v = ((const float4*)a.src[j])[i];
    ushort4 o;
    o.x = f2bu(v.x); o.y = f2bu(v.y); o.z = f2bu(v.z); o.w = f2bu(v.w);
    ((ushort4*)a.dst[j])[i] = o;
  }
}

// ---------------------------------------------------------------------------
// 128x128-tile GEMM body, BK=32, 4 waves, triple-buffered counted-vmcnt
// staging (R7-verified). EPI: 0 = QK split write (Q pre-scaled QSCALE);
// 2 = +bias +fp32 resid -> bf16; 3 = +bias gelu -> bf16; 4 = +bias +bf16 resid.
template<int EPI>
DEVI void gemm_body(const u16* __restrict__ A, const u16* __restrict__ Bm,
                    const float* __restrict__ bias0, const float* __restrict__ bias1,
                    const float* __restrict__ residf, const u16* __restrict__ residb,
                    u16* __restrict__ out0, u16* __restrict__ out1,
                    int N, int K, int bx, int by,
                    u16 (&As)[3][128 * 32], u16 (&Bs)[3][128 * 32]) {
  const int t = threadIdx.x;
  const int w = t >> 6, l = t & 63;
  const int li = l & 15, grp = l >> 4;
  const int n0 = bx * 128, m0 = by * 128;
  const int wr = w >> 1, wc = w & 1;

  f32x4 acc[4][4] = {};

  const int arow = w * 16 + (l >> 2);
  const int acol = (l & 3) * 8;
  const u16* Ag = A + (size_t)(m0 + arow) * K + acol;
  const u16* Bg = Bm + (size_t)(n0 + arow) * K + acol;
  const int NT = K >> 5;

  auto stage = [&](int buf, int kt) {
    u16* Asw = &As[buf][(w * 16) * 32];
    u16* Bsw = &Bs[buf][(w * 16) * 32];
    const int k0 = kt * 32;
    gload_lds16(Ag + k0, Asw);
    gload_lds16(Ag + (size_t)64 * K + k0, Asw + 64 * 32);
    gload_lds16(Bg + k0, Bsw);
    gload_lds16(Bg + (size_t)64 * K + k0, Bsw + 64 * 32);
  };

  stage(0, 0); stage(1, 1);
  asm volatile("s_waitcnt vmcnt(4)\n\ts_barrier" ::: "memory");

  for (int kt = 0; kt < NT; ++kt) {
    const int bt = kt % 3;
    const bool pre = (kt + 2 < NT);
    if (pre) stage((kt + 2) % 3, kt + 2);
    bf16x8 af[4], bfr[4];
#pragma unroll
    for (int m = 0; m < 4; ++m)
      af[m] = ld_frag(&As[bt][(wr * 64 + m * 16 + li) * 32 + grp * 8]);
#pragma unroll
    for (int n = 0; n < 4; ++n)
      bfr[n] = ld_frag(&Bs[bt][(wc * 64 + n * 16 + li) * 32 + grp * 8]);
    __builtin_amdgcn_s_setprio(1);
#pragma unroll
    for (int m = 0; m < 4; ++m)
#pragma unroll
      for (int n = 0; n < 4; ++n)
        acc[m][n] = __builtin_amdgcn_mfma_f32_16x16x32_bf16(af[m], bfr[n], acc[m][n], 0, 0, 0);
    __builtin_amdgcn_s_setprio(0);
    if (pre) asm volatile("s_waitcnt vmcnt(4) lgkmcnt(0)\n\ts_barrier" ::: "memory");
    else     asm volatile("s_waitcnt vmcnt(0) lgkmcnt(0)\n\ts_barrier" ::: "memory");
  }

#pragma unroll
  for (int m = 0; m < 4; ++m) {
#pragma unroll
    for (int n = 0; n < 4; ++n) {
#pragma unroll
      for (int j = 0; j < 4; ++j) {
        const int row = m0 + wr * 64 + m * 16 + grp * 4 + j;
        const int col = n0 + wc * 64 + n * 16 + li;
        float v = acc[m][n][j];
        if constexpr (EPI == 0) {
          v += (col < D_) ? bias0[col] : bias1[col - D_];
          if (col < D_) v *= QSCALE;   // fold (1/sqrt(DH))*log2e into Q
          const int b = row >> 10, i = row & (N_ - 1);
          int c2 = (col < D_) ? col : col - D_;
          u16* dst = (col < D_) ? out0 : out1;
          dst[(((size_t)(b * H_ + (c2 >> 6))) * N_ + i) * DH_ + (c2 & 63)] = f2bu(v);
        } else if constexpr (EPI == 2) {
          v += bias0[col] + residf[(size_t)row * N + col];
          out0[(size_t)row * N + col] = f2bu(v);
        } else if constexpr (EPI == 3) {  // gelu(exact) -> bf16
          v += bias0[col];
          float gel = 0.5f * v * (1.0f + erff(v * 0.70710678118654752440f));
          out0[(size_t)row * N + col] = f2bu(gel);
        } else {  // EPI == 4
          v += bias0[col] + b2f(residb[(size_t)row * N + col]);
          out0[(size_t)row * N + col] = f2bu(v);
        }
      }
    }
  }
}

// V-projection tile with B-side row GATHER: C = Wv(128 rows) x Xc(128 slots)^T,
// Xc rows fetched through idx (per-lane global_load_lds source addresses).
// Writes vT[b] compacted: vTb_b[row*1024 + slot] (coalesced in slot).
DEVI void gemm_v_body(const u16* __restrict__ Wv, const u16* __restrict__ Xbf,
                      const float* __restrict__ bv, const int* __restrict__ idxb,
                      int b, int tile, int c, u16* __restrict__ vTb,
                      u16 (&As)[3][128 * 32], u16 (&Bs)[3][128 * 32]) {
  constexpr int K = 768, NT = 24;
  const int t = threadIdx.x;
  const int w = t >> 6, l = t & 63;
  const int li = l & 15, grp = l >> 4;
  const int wr = w >> 1, wc = w & 1;
  const int m0 = c * 128;

  f32x4 acc[4][4] = {};

  const int arow = w * 16 + (l >> 2);
  const int acol = (l & 3) * 8;
  const int tok0 = idxb[tile * 128 + arow];
  const int tok1 = idxb[tile * 128 + arow + 64];
  const u16* Ag = Wv + (size_t)(m0 + arow) * K + acol;
  const u16* Bg0 = Xbf + ((size_t)b * N_ + tok0) * K + acol;
  const u16* Bg1 = Xbf + ((size_t)b * N_ + tok1) * K + acol;

  auto stage = [&](int buf, int kt) {
    u16* Asw = &As[buf][(w * 16) * 32];
    u16* Bsw = &Bs[buf][(w * 16) * 32];
    const int k0 = kt * 32;
    gload_lds16(Ag + k0, Asw);
    gload_lds16(Ag + (size_t)64 * K + k0, Asw + 64 * 32);
    gload_lds16(Bg0 + k0, Bsw);
    gload_lds16(Bg1 + k0, Bsw + 64 * 32);
  };

  stage(0, 0); stage(1, 1);
  asm volatile("s_waitcnt vmcnt(4)\n\ts_barrier" ::: "memory");

  for (int kt = 0; kt < NT; ++kt) {
    const int bt = kt % 3;
    const bool pre = (kt + 2 < NT);
    if (pre) stage((kt + 2) % 3, kt + 2);
    bf16x8 af[4], bfr[4];
#pragma unroll
    for (int m = 0; m < 4; ++m)
      af[m] = ld_frag(&As[bt][(wr * 64 + m * 16 + li) * 32 + grp * 8]);
#pragma unroll
    for (int n = 0; n < 4; ++n)
      bfr[n] = ld_frag(&Bs[bt][(wc * 64 + n * 16 + li) * 32 + grp * 8]);
    __builtin_amdgcn_s_setprio(1);
#pragma unroll
    for (int m = 0; m < 4; ++m)
#pragma unroll
      for (int n = 0; n < 4; ++n)
        acc[m][n] = __builtin_amdgcn_mfma_f32_16x16x32_bf16(af[m], bfr[n], acc[m][n], 0, 0, 0);
    __builtin_amdgcn_s_setprio(0);
    if (pre) asm volatile("s_waitcnt vmcnt(4) lgkmcnt(0)\n\ts_barrier" ::: "memory");
    else     asm volatile("s_waitcnt vmcnt(0) lgkmcnt(0)\n\ts_barrier" ::: "memory");
  }

  u16* outb = vTb + (size_t)b * D_ * N_;
#pragma unroll
  for (int m = 0; m < 4; ++m) {
#pragma unroll
    for (int n = 0; n < 4; ++n) {
      const int slot = tile * 128 + wc * 64 + n * 16 + li;
#pragma unroll
      for (int j = 0; j < 4; ++j) {
        const int row = m0 + wr * 64 + m * 16 + grp * 4 + j;  // = h*64+dh
        outb[(size_t)row * N_ + slot] = f2bu(acc[m][n][j] + bv[row]);
      }
    }
  }
}

// Standalone 128^2 GEMM with XCD swizzle (EPI 2,3,4 shapes).
template<int EPI>
__global__ __launch_bounds__(256, 3)
void gemm_bt(const u16* __restrict__ A, const u16* __restrict__ Bm,
             const float* __restrict__ bias0,
             const float* __restrict__ residf, const u16* __restrict__ residb,
             u16* __restrict__ out0, int N, int K) {
  __shared__ u16 As[3][128 * 32];
  __shared__ u16 Bs[3][128 * 32];
  const int nwg = gridDim.x * gridDim.y;
  int id = blockIdx.y * gridDim.x + blockIdx.x;
  id = (id & 7) * (nwg >> 3) + (id >> 3);
  const int by = id / gridDim.x;
  const int bx = id - by * gridDim.x;
  gemm_body<EPI>(A, Bm, bias0, nullptr, residf, residb, out0, nullptr,
                 N, K, bx, by, As, Bs);
}

// Merged QK-projection (ids 0..767, full tokens) + compacted V-projection
// (ids 768..1151, early-exit tiles beyond nkp[b]).
__global__ __launch_bounds__(256, 3)
void gemm_qkv(const u16* __restrict__ Xbf, const u16* __restrict__ Wqk,
              const u16* __restrict__ Wv,
              const float* __restrict__ bq, const float* __restrict__ bk,
              const float* __restrict__ bv,
              const int* __restrict__ idx, const int* __restrict__ nkparr,
              u16* __restrict__ qb, u16* __restrict__ kb, u16* __restrict__ vTb) {
  __shared__ u16 As[3][128 * 32];
  __shared__ u16 Bs[3][128 * 32];
  constexpr int nwg = 1152;
  int id = blockIdx.x;
  id = (id & 7) * (nwg >> 3) + (id >> 3);   // bijective XCD chunking
  if (id < 768) {
    const int by = id / 12, bx = id - by * 12;
    gemm_body<0>(Xbf, Wqk, bq, bk, nullptr, nullptr, qb, kb,
                 1536, 768, bx, by, As, Bs);
  } else {
    const int vs = id - 768;                 // 0..383
    const int c = vs / 64, ts = vs - c * 64;
    const int b = ts >> 3, tile = ts & 7;
    if (tile * 128 >= nkparr[b]) return;
    gemm_v_body(Wv, Xbf, bv, idx + b * N_, b, tile, c, vTb, As, Bs);
  }
}

// ---------------------------------------------------------------------------
// Flash attention over COMPACTED keys: loop bound nkp[b] (mult of 64), K rows
// gathered via idx at stage time (per-lane gload_lds source), V/mask already
// compacted. Softmax in base-2 (Q pre-scaled by log2e/8, exp2f).
__global__ __launch_bounds__(512, 4)
void attn(const u16* __restrict__ q, const u16* __restrict__ k, const u16* __restrict__ vT,
          const u16* __restrict__ mp, const int* __restrict__ idx,
          const int* __restrict__ nkparr, u16* __restrict__ outp) {
  const int nwg = gridDim.x;
  const int p = blockIdx.x;
  const int lid = (p & 7) * (nwg >> 3) + (p >> 3);
  const int bh_i = lid >> 3;       // (b*H + h)
  const int qblk = lid & 7;
  const int b = bh_i / H_, h = bh_i - (bh_i / H_) * H_;
  const int w = threadIdx.x >> 6, l = threadIdx.x & 63;
  const int li = l & 15, grp = l >> 4;
  const int qw = qblk * 128 + w * 16;
  const size_t bh = (size_t)bh_i;
  const int nkp = nkparr[b];
  const int* idxb = idx + b * N_;

  __shared__ u16 Kt[2][64 * 64];   // [slot-local][d], swizzled
  __shared__ u16 Vt[2][64 * 64];   // [d][slot-local], swizzled
  __shared__ u16 P[8][16 * 64];    // per-wave [q=li][slot-local], swizzled

  const u16* kbase = k + bh * N_ * DH_;
  const u16* vbase = vT + bh * DH_ * N_;

  const int srow_off = l >> 3;          // 0..7
  const int sg = l & 7;                 // dest granule
  const int r0 = w * 8;
  auto stageK = [&](int buf, int kj0) {
    const int row = r0 + srow_off;
    const int tok = idxb[kj0 + row];    // gather token for this slot
    const int gp = sg ^ (row & 7);
    gload_lds16(kbase + (size_t)tok * DH_ + gp * 8, &Kt[buf][r0 * 64]);
  };
  auto stageV = [&](int buf, int kj0) {
    const int row = r0 + srow_off;
    const int gp = sg ^ (row & 7);
    gload_lds16(vbase + (size_t)row * N_ + kj0 + gp * 8, &Vt[buf][r0 * 64]);
  };

  const u16* qp = q + (bh * N_ + qw) * DH_;
  const bf16x8 bq0 = ld_frag(qp + li * DH_ + grp * 8);
  const bf16x8 bq1 = ld_frag(qp + li * DH_ + 32 + grp * 8);

  f32x4 accO[4] = {};            // O^T: d = t2*16+grp*4+j, q = li
  float m = -INFINITY, lsum = 0.f;

  u16* Pw = &P[w][0];
  const int sw = (li & 7) << 3;
  const int prow = li * 64;
  const u16* mrow = mp + bh * (N_ / 16) * N_ + qw + li;

  if (nkp > 0) { stageK(0, 0); stageV(0, 0); }
  __syncthreads();
  int cur = 0;

  for (int kj0 = 0; kj0 < nkp; kj0 += 64) {
    if (kj0 + 64 < nkp) { stageK(cur ^ 1, kj0 + 64); stageV(cur ^ 1, kj0 + 64); }
    unsigned mword[4];
#pragma unroll
    for (int t = 0; t < 4; ++t) mword[t] = mrow[(size_t)((kj0 >> 4) + t) * N_];

    f32x4 s[4];
    __builtin_amdgcn_s_setprio(1);
#pragma unroll
    for (int t = 0; t < 4; ++t) {
      const int row = t * 16 + li;
      const int rs = row & 7;
      const bf16x8 ka0 = ld_frag(&Kt[cur][row * 64 + ((grp ^ rs) * 8)]);
      const bf16x8 ka1 = ld_frag(&Kt[cur][row * 64 + (((grp + 4) ^ rs) * 8)]);
      f32x4 z = {0.f, 0.f, 0.f, 0.f};
      z = __builtin_amdgcn_mfma_f32_16x16x32_bf16(ka0, bq0, z, 0, 0, 0);
      z = __builtin_amdgcn_mfma_f32_16x16x32_bf16(ka1, bq1, z, 0, 0, 0);
      s[t] = z;
    }
    __builtin_amdgcn_s_setprio(0);

    // mask (scores already base-2-scaled via Q); lane holds 16 for q = li
    float sv[16];
#pragma unroll
    for (int t = 0; t < 4; ++t) {
      const unsigned mb = (mword[t] >> (grp * 4)) & 0xFu;
#pragma unroll
      for (int j = 0; j < 4; ++j)
        sv[t * 4 + j] = ((mb >> j) & 1u) ? -INFINITY : s[t][j];
    }
    const float a0 = fmaxf(fmaxf(sv[0], sv[1]), sv[2]);
    const float a1 = fmaxf(fmaxf(sv[3], sv[4]), sv[5]);
    const float a2 = fmaxf(fmaxf(sv[6], sv[7]), sv[8]);
    const float a3 = fmaxf(fmaxf(sv[9], sv[10]), sv[11]);
    const float a4 = fmaxf(fmaxf(sv[12], sv[13]), sv[14]);
    float rmax = fmaxf(fmaxf(fmaxf(a0, a1), fmaxf(a2, a3)), fmaxf(a4, sv[15]));
    rmax = fmaxf(rmax, __shfl_xor(rmax, 16));
    rmax = fmaxf(rmax, __shfl_xor(rmax, 32));
    // defer-max (threshold in base-2 units)
    if (!__all(rmax <= m + THR2)) {
      const float mnew = fmaxf(m, rmax);
      const float scal = (m == -INFINITY) ? 0.f : exp2f(m - mnew);
      lsum *= scal;
#pragma unroll
      for (int t2 = 0; t2 < 4; ++t2) accO[t2] *= scal;
      m = mnew;
    }
    const float msafe = (m == -INFINITY) ? 0.f : m;
    float psum = 0.f;
    float pv[16];
#pragma unroll
    for (int i = 0; i < 16; ++i) {
      const float e = exp2f(sv[i] - msafe);  // exp2(-inf)=0 zeroes masked
      pv[i] = e;
      psum += e;
    }
    psum += __shfl_xor(psum, 16);
    psum += __shfl_xor(psum, 32);
    lsum += psum;
    // P -> LDS (bf16 via paired cvt_pk), swizzled
#pragma unroll
    for (int t = 0; t < 4; ++t) {
      bf16x2 plo = { (__bf16)pv[t * 4 + 0], (__bf16)pv[t * 4 + 1] };
      bf16x2 phi = { (__bf16)pv[t * 4 + 2], (__bf16)pv[t * 4 + 3] };
      uint2 pk;
      pk.x = __builtin_bit_cast(unsigned, plo);
      pk.y = __builtin_bit_cast(unsigned, phi);
      *(uint2*)&Pw[prow + ((t * 16 + grp * 4) ^ sw)] = pk;
    }
    // PV: O^T[d][q] += V^T[d][slot] * P^T[slot][q]
    __builtin_amdgcn_s_setprio(1);
#pragma unroll
    for (int kc = 0; kc < 2; ++kc) {
      const bf16x8 pb = ld_frag(&Pw[prow + ((kc * 32 + grp * 8) ^ sw)]);
#pragma unroll
      for (int t2 = 0; t2 < 4; ++t2) {
        const int row = t2 * 16 + li;
        const bf16x8 va = ld_frag(&Vt[cur][row * 64 + (((kc * 4 + grp) ^ (row & 7)) * 8)]);
        accO[t2] = __builtin_amdgcn_mfma_f32_16x16x32_bf16(va, pb, accO[t2], 0, 0, 0);
      }
    }
    __builtin_amdgcn_s_setprio(0);
    __syncthreads();
    cur ^= 1;
  }
  const float inv = (lsum > 0.f) ? 1.0f / lsum : 0.f;  // all-masked row -> 0
  u16* op = outp + ((size_t)b * N_ + qw + li) * D_ + h * DH_;
#pragma unroll
  for (int t2 = 0; t2 < 4; ++t2) {
    bf16x2 o01 = { (__bf16)(accO[t2][0] * inv), (__bf16)(accO[t2][1] * inv) };
    bf16x2 o23 = { (__bf16)(accO[t2][2] * inv), (__bf16)(accO[t2][3] * inv) };
    uint2 ov;
    ov.x = __builtin_bit_cast(unsigned, o01);
    ov.y = __builtin_bit_cast(unsigned, o23);
    *(uint2*)&op[t2 * 16 + grp * 4] = ov;
  }
}

// ---------------------------------------------------------------------------
// Row LayerNorm over bf16 input (768 = 256*3).
template<int OUTF32>
__global__ __launch_bounds__(256)
void ln_kernel(const u16* __restrict__ x, const float* __restrict__ g,
               const float* __restrict__ be, u16* __restrict__ ybf,
               float* __restrict__ yf) {
  const int row = blockIdx.x;
  const int t = threadIdx.x;
  const u16* xr = x + (size_t)row * D_;
  const float v0 = b2f(xr[t]), v1 = b2f(xr[t + 256]), v2 = b2f(xr[t + 512]);
  float s = v0 + v1 + v2;
  float s2 = v0 * v0 + v1 * v1 + v2 * v2;
#pragma unroll
  for (int d = 1; d < 64; d <<= 1) { s += __shfl_xor(s, d); s2 += __shfl_xor(s2, d); }
  __shared__ float red[8];
  const int w = t >> 6;
  if ((t & 63) == 0) { red[w] = s; red[4 + w] = s2; }
  __syncthreads();
  s = red[0] + red[1] + red[2] + red[3];
  s2 = red[4] + red[5] + red[6] + red[7];
  const float mu = s * (1.0f / D_);
  const float var = fmaxf(s2 * (1.0f / D_) - mu * mu, 0.0f);
  const float rstd = rsqrtf(var + 1e-5f);
#pragma unroll
  for (int c = 0; c < 3; ++c) {
    const int idx2 = t + c * 256;
    const float vv = (c == 0) ? v0 : (c == 1) ? v1 : v2;
    const float o = (vv - mu) * rstd * g[idx2] + be[idx2];
    if constexpr (OUTF32) yf[(size_t)row * D_ + idx2] = o;
    else ybf[(size_t)row * D_ + idx2] = f2bu(o);
  }
}

// ---------------------------------------------------------------------------
extern "C" void kernel_launch(void* const* d_in, const int* in_sizes, int n_in,
                              void* d_out, int out_size, void* d_ws, size_t ws_size,
                              hipStream_t stream) {
  (void)in_sizes; (void)n_in; (void)out_size; (void)ws_size;
  const float* nodes = (const float*)d_in[0];
  const float* rel   = (const float*)d_in[1];
  const int*   nmask = (const int*)d_in[2];
  const float* Wq = (const float*)d_in[3];
  const float* bq = (const float*)d_in[4];
  const float* Wk = (const float*)d_in[5];
  const float* bk = (const float*)d_in[6];
  const float* Wv = (const float*)d_in[7];
  const float* bv = (const float*)d_in[8];
  const float* Wo = (const float*)d_in[9];
  const float* bo = (const float*)d_in[10];
  const float* ln1g = (const float*)d_in[11];
  const float* ln1b = (const float*)d_in[12];
  const float* W1 = (const float*)d_in[13];
  const float* b1 = (const float*)d_in[14];
  const float* W2 = (const float*)d_in[15];
  const float* b2 = (const float*)d_in[16];
  const float* ln2g = (const float*)d_in[17];
  const float* ln2b = (const float*)d_in[18];
  float* out = (float*)d_out;

  char* ws = (char*)d_ws;
  u16* Wqk_bf = (u16*)(ws + 0);          // [Wq;Wk] 1536x768
  u16* Wv_bf  = (u16*)(ws + 2359296);
  u16* Wo_bf  = (u16*)(ws + 3538944);
  u16* W1_bf  = (u16*)(ws + 4718592);
  u16* W2_bf  = (u16*)(ws + 7077888);
  u16* Xbf    = (u16*)(ws + 9437184);    // nodes bf16; later reused as attn-out
  u16* qb     = (u16*)(ws + 22020096);   // (b,h,i,dh)
  u16* kb     = (u16*)(ws + 34603008);   // (b,h,token,dh) full
  u16* vTb    = (u16*)(ws + 47185920);   // (b,h,dh,slot) compacted
  u16* mwb    = (u16*)(ws + 59768832);   // packed mask words (slot-indexed)
  u16* prehb  = (u16*)(ws + 22020096);   // bf16, overlays dead qb
  u16* hbf    = (u16*)(ws + 47185920);   // overlays dead vT
  u16* f1b    = (u16*)(ws + 59768832);   // overlays dead mask
  u16* preob  = (u16*)(ws + 84934656);   // bf16
  int* idx    = (int*)(ws + 100663296);  // [8][1024] compacted token indices
  int* nkparr = (int*)(ws + 100696064);  // [0..7]=padded count, [8..15]=exact
  u16* attno  = Xbf;

  const dim3 blk(256);
  // key compaction (tiny)
  compact<<<8, dim3(1024), 0, stream>>>(nmask, idx, nkparr);
  // mask packing (gathered) + all converts in ONE launch
  CvtArgs ca;
  ca.src[0] = Wq; ca.src[1] = Wk; ca.src[2] = Wv; ca.src[3] = Wo;
  ca.src[4] = W1; ca.src[5] = W2; ca.src[6] = nodes;
  ca.dst[0] = Wqk_bf; ca.dst[1] = Wqk_bf + 768 * 768; ca.dst[2] = Wv_bf;
  ca.dst[3] = Wo_bf; ca.dst[4] = W1_bf; ca.dst[5] = W2_bf; ca.dst[6] = Xbf;
  ca.n4[0] = ca.n4[1] = ca.n4[2] = ca.n4[3] = 147456;
  ca.n4[4] = ca.n4[5] = 294912; ca.n4[6] = 1572864;
  ca.start[0] = 2048; ca.start[1] = 2624; ca.start[2] = 3200; ca.start[3] = 3776;
  ca.start[4] = 4352; ca.start[5] = 5504; ca.start[6] = 6656; ca.start[7] = 12800;
  prep_all<<<12800, blk, 0, stream>>>(ca, rel, idx, nkparr, mwb);
  // fused QK projection (full) + compacted V projection in ONE launch
  gemm_qkv<<<1152, blk, 0, stream>>>(Xbf, Wqk_bf, Wv_bf, bq, bk, bv,
                                     idx, nkparr, qb, kb, vTb);
  // attention over compacted keys
  attn<<<768, dim3(512), 0, stream>>>(qb, kb, vTb, mwb, idx, nkparr, attno);
  // out-proj + fp32 residual(nodes) -> bf16 pre_h
  gemm_bt<2><<<dim3(6, 64), blk, 0, stream>>>(attno, Wo_bf, bo, nodes, nullptr,
                                              prehb, 768, 768);
  // LN1 -> bf16 h
  ln_kernel<0><<<8192, blk, 0, stream>>>(prehb, ln1g, ln1b, hbf, nullptr);
  // FFN1 + gelu -> bf16
  gemm_bt<3><<<dim3(12, 64), blk, 0, stream>>>(hbf, W1_bf, b1, nullptr, nullptr,
                                               f1b, 1536, 768);
  // FFN2 + bf16 residual(h) -> bf16 pre_out
  gemm_bt<4><<<dim3(6, 64), blk, 0, stream>>>(f1b, W2_bf, b2, nullptr, hbf,
                                              preob, 768, 1536);
  // LN2 -> fp32 output
  ln_kernel<1><<<8192, blk, 0, stream>>>(preob, ln2g, ln2b, nullptr, out);
}

// Round 11
// 303.197 us; speedup vs baseline: 1.0300x; 1.0300x over previous
//
#include <hip/hip_runtime.h>
#include <stdint.h>
#include <math.h>

typedef unsigned short u16;
typedef __bf16 bf16x8 __attribute__((ext_vector_type(8)));
typedef __bf16 bf16x2 __attribute__((ext_vector_type(2)));
typedef unsigned short u16x8 __attribute__((ext_vector_type(8)));
typedef unsigned short u16x4 __attribute__((ext_vector_type(4)));
typedef float f32x4 __attribute__((ext_vector_type(4)));

#define DEVI __device__ __forceinline__

constexpr int B_ = 8, N_ = 1024, D_ = 768, H_ = 12, DH_ = 64, DF_ = 1536;
// (1/sqrt(64)) * log2(e): QK^T scores land in base-2 domain (exp2 softmax)
constexpr float QSCALE = 0.18033688011112042f;
constexpr float THR2 = 11.5415603f;   // defer-max threshold 8 * log2(e)

// float -> bf16 bits, round-to-nearest-even (finite inputs only)
DEVI u16 f2bu(float f) {
  unsigned x = __builtin_bit_cast(unsigned, f);
  x += 0x7FFFu + ((x >> 16) & 1u);
  return (u16)(x >> 16);
}
DEVI float b2f(u16 u) { return __builtin_bit_cast(float, (unsigned)u << 16); }

DEVI bf16x8 ld_frag(const u16* p) {
  return __builtin_bit_cast(bf16x8, *(const u16x8*)p);
}

DEVI void gload_lds16(const u16* g, u16* l) {
  __builtin_amdgcn_global_load_lds(
      (const __attribute__((address_space(1))) void*)g,
      (__attribute__((address_space(3))) void*)l, 16, 0, 0);
}

// ---------------------------------------------------------------------------
// prep_all: ONE launch = relation-mask bit-packing (blocks 0..2047, dense
// coalesced rel read) + all seven fp32->bf16 converts (blocks 2048..12799).
struct CvtArgs {
  const float* src[7];
  u16* dst[7];
  int n4[7];
  int start[8];  // cumulative block starts (offset by 2048)
};
__global__ __launch_bounds__(256)
void prep_all(CvtArgs a, const float* __restrict__ rel, const int* __restrict__ nm,
              u16* __restrict__ mp) {
  const int gb0 = blockIdx.x;
  const int t = threadIdx.x;
  if (gb0 < 2048) {
    // ---- mask packing: id -> (k0, q0, b) as in dim3(4,64,8) flattening
    const int b = gb0 >> 8, q0 = ((gb0 >> 2) & 63) * 16, k0 = (gb0 & 3) * 256;
    __shared__ u16 w12[16][256];
    const int key_ok = nm[(b << 10) + k0 + t];
    const float th = 1e-4f;
#pragma unroll 1
    for (int it = 0; it < 16; ++it) {
      unsigned bits;
      if (!key_ok) {
        bits = 0xFFFu;
      } else {
        const size_t idx = (((size_t)(b << 10) + q0 + it) << 10) + k0 + t;
        const float2* rp = (const float2*)(rel + idx * 10);
        float2 a0 = rp[0], a1 = rp[1], a2 = rp[2], a3 = rp[3], a4 = rp[4];
        bits  = (a0.x < th ? 1u : 0u)   | (a0.y < th ? 2u : 0u)
              | (a1.x < th ? 4u : 0u)   | (a1.y < th ? 8u : 0u)
              | (a2.x < th ? 16u : 0u)  | (a2.y < th ? 32u : 0u)
              | (a3.x < th ? 64u : 0u)  | (a3.y < th ? 128u : 0u)
              | (a4.x < th ? 256u : 0u) | (a4.y < th ? 512u : 0u);
      }
      w12[it][t ^ ((it & 7) << 1)] = (u16)bits;
    }
    __syncthreads();
    const int ql = t & 15, kt = t >> 4;
    unsigned wv[16];
#pragma unroll
    for (int j2 = 0; j2 < 8; ++j2) {
      const int e = (kt * 16 + j2 * 2) ^ ((ql & 7) << 1);
      wv[j2 * 2] = w12[ql][e];
      wv[j2 * 2 + 1] = w12[ql][e + 1];
    }
#pragma unroll
    for (int h = 0; h < 12; ++h) {
      unsigned word = 0;
#pragma unroll
      for (int j = 0; j < 16; ++j) word |= ((wv[j] >> h) & 1u) << j;
      mp[(((size_t)(b * H_ + h)) * (N_ / 16) + (k0 >> 4) + kt) * N_ + q0 + ql] = (u16)word;
    }
  } else {
    // ---- converts
    int j = 0;
    while (gb0 >= a.start[j + 1]) ++j;
    const int i = (gb0 - a.start[j]) * 256 + t;
    if (i >= a.n4[j]) return;
    float4 v = ((const float4*)a.src[j])[i];
    ushort4 o;
    o.x = f2bu(v.x); o.y = f2bu(v.y); o.z = f2bu(v.z); o.w = f2bu(v.w);
    ((ushort4*)a.dst[j])[i] = o;
  }
}

// ---------------------------------------------------------------------------
// 128x128-tile GEMM body, BK=32, 4 waves, triple-buffered counted-vmcnt
// staging (R7-verified). EPI: 0 = QK split write (Q pre-scaled QSCALE);
// 1 = vT write (b,h,dh,i); 3 = +bias gelu -> bf16; 4 = +bias +bf16 resid.
template<int EPI>
DEVI void gemm_body(const u16* __restrict__ A, const u16* __restrict__ Bm,
                    const float* __restrict__ bias0, const float* __restrict__ bias1,
                    const u16* __restrict__ residb,
                    u16* __restrict__ out0, u16* __restrict__ out1,
                    int N, int K, int bx, int by,
                    u16 (&As)[3][128 * 32], u16 (&Bs)[3][128 * 32]) {
  const int t = threadIdx.x;
  const int w = t >> 6, l = t & 63;
  const int li = l & 15, grp = l >> 4;
  const int n0 = bx * 128, m0 = by * 128;
  const int wr = w >> 1, wc = w & 1;

  f32x4 acc[4][4] = {};

  const int arow = w * 16 + (l >> 2);
  const int acol = (l & 3) * 8;
  const u16* Ag = A + (size_t)(m0 + arow) * K + acol;
  const u16* Bg = Bm + (size_t)(n0 + arow) * K + acol;
  const int NT = K >> 5;

  auto stage = [&](int buf, int kt) {
    u16* Asw = &As[buf][(w * 16) * 32];
    u16* Bsw = &Bs[buf][(w * 16) * 32];
    const int k0 = kt * 32;
    gload_lds16(Ag + k0, Asw);
    gload_lds16(Ag + (size_t)64 * K + k0, Asw + 64 * 32);
    gload_lds16(Bg + k0, Bsw);
    gload_lds16(Bg + (size_t)64 * K + k0, Bsw + 64 * 32);
  };

  stage(0, 0); stage(1, 1);
  asm volatile("s_waitcnt vmcnt(4)\n\ts_barrier" ::: "memory");

  for (int kt = 0; kt < NT; ++kt) {
    const int bt = kt % 3;
    const bool pre = (kt + 2 < NT);
    if (pre) stage((kt + 2) % 3, kt + 2);
    bf16x8 af[4], bfr[4];
#pragma unroll
    for (int m = 0; m < 4; ++m)
      af[m] = ld_frag(&As[bt][(wr * 64 + m * 16 + li) * 32 + grp * 8]);
#pragma unroll
    for (int n = 0; n < 4; ++n)
      bfr[n] = ld_frag(&Bs[bt][(wc * 64 + n * 16 + li) * 32 + grp * 8]);
    __builtin_amdgcn_s_setprio(1);
#pragma unroll
    for (int m = 0; m < 4; ++m)
#pragma unroll
      for (int n = 0; n < 4; ++n)
        acc[m][n] = __builtin_amdgcn_mfma_f32_16x16x32_bf16(af[m], bfr[n], acc[m][n], 0, 0, 0);
    __builtin_amdgcn_s_setprio(0);
    if (pre) asm volatile("s_waitcnt vmcnt(4) lgkmcnt(0)\n\ts_barrier" ::: "memory");
    else     asm volatile("s_waitcnt vmcnt(0) lgkmcnt(0)\n\ts_barrier" ::: "memory");
  }

#pragma unroll
  for (int m = 0; m < 4; ++m) {
#pragma unroll
    for (int n = 0; n < 4; ++n) {
#pragma unroll
      for (int j = 0; j < 4; ++j) {
        const int row = m0 + wr * 64 + m * 16 + grp * 4 + j;
        const int col = n0 + wc * 64 + n * 16 + li;
        float v = acc[m][n][j];
        if constexpr (EPI == 0) {
          v += (col < D_) ? bias0[col] : bias1[col - D_];
          if (col < D_) v *= QSCALE;   // fold (1/sqrt(DH))*log2e into Q
          const int b = row >> 10, i = row & (N_ - 1);
          int c2 = (col < D_) ? col : col - D_;
          u16* dst = (col < D_) ? out0 : out1;
          dst[(((size_t)(b * H_ + (c2 >> 6))) * N_ + i) * DH_ + (c2 & 63)] = f2bu(v);
        } else if constexpr (EPI == 1) {
          v += bias0[row];
          const int b = col >> 10, i = col & (N_ - 1);
          out0[(((size_t)(b * H_ + (row >> 6))) * DH_ + (row & 63)) * N_ + i] = f2bu(v);
        } else if constexpr (EPI == 3) {  // gelu(exact) -> bf16
          v += bias0[col];
          float gel = 0.5f * v * (1.0f + erff(v * 0.70710678118654752440f));
          out0[(size_t)row * N + col] = f2bu(gel);
        } else {  // EPI == 4: +bias + bf16 resid -> bf16
          v += bias0[col] + b2f(residb[(size_t)row * N + col]);
          out0[(size_t)row * N + col] = f2bu(v);
        }
      }
    }
  }
}

// Standalone 128^2 GEMM with XCD swizzle (EPI 3,4 shapes).
template<int EPI>
__global__ __launch_bounds__(256, 3)
void gemm_bt(const u16* __restrict__ A, const u16* __restrict__ Bm,
             const float* __restrict__ bias0, const u16* __restrict__ residb,
             u16* __restrict__ out0, int N, int K) {
  __shared__ u16 As[3][128 * 32];
  __shared__ u16 Bs[3][128 * 32];
  const int nwg = gridDim.x * gridDim.y;
  int id = blockIdx.y * gridDim.x + blockIdx.x;
  id = (id & 7) * (nwg >> 3) + (id >> 3);
  const int by = id / gridDim.x;
  const int bx = id - by * gridDim.x;
  gemm_body<EPI>(A, Bm, bias0, nullptr, residb, out0, nullptr,
                 N, K, bx, by, As, Bs);
}

// Merged QK-projection (blocks 0..767) + V-projection (768..1151).
__global__ __launch_bounds__(256, 3)
void gemm_qkv(const u16* __restrict__ Xbf, const u16* __restrict__ Wqk,
              const u16* __restrict__ Wv,
              const float* __restrict__ bq, const float* __restrict__ bk,
              const float* __restrict__ bv,
              u16* __restrict__ qb, u16* __restrict__ kb, u16* __restrict__ vTb) {
  __shared__ u16 As[3][128 * 32];
  __shared__ u16 Bs[3][128 * 32];
  constexpr int nwg = 1152;
  int id = blockIdx.x;
  id = (id & 7) * (nwg >> 3) + (id >> 3);   // bijective XCD chunking
  if (id < 768) {
    const int by = id / 12, bx = id - by * 12;
    gemm_body<0>(Xbf, Wqk, bq, bk, nullptr, qb, kb,
                 1536, 768, bx, by, As, Bs);
  } else {
    const int v = id - 768;
    const int by = v / 64, bx = v - by * 64;
    gemm_body<1>(Wv, Xbf, bv, nullptr, nullptr, vTb, nullptr,
                 8192, 768, bx, by, As, Bs);
  }
}

// ---------------------------------------------------------------------------
// Flash attention, swapped-operand + LDS-staged K/V, base-2 lean softmax.
__global__ __launch_bounds__(512, 4)
void attn(const u16* __restrict__ q, const u16* __restrict__ k, const u16* __restrict__ vT,
          const u16* __restrict__ mp, u16* __restrict__ outp) {
  const int nwg = gridDim.x;
  const int p = blockIdx.x;
  const int lid = (p & 7) * (nwg >> 3) + (p >> 3);
  const int bh_i = lid >> 3;       // (b*H + h)
  const int qblk = lid & 7;
  const int b = bh_i / H_, h = bh_i - (bh_i / H_) * H_;
  const int w = threadIdx.x >> 6, l = threadIdx.x & 63;
  const int li = l & 15, grp = l >> 4;
  const int qw = qblk * 128 + w * 16;
  const size_t bh = (size_t)bh_i;

  __shared__ u16 Kt[2][64 * 64];   // [k-local][d], swizzled
  __shared__ u16 Vt[2][64 * 64];   // [d][k-local], swizzled
  __shared__ u16 P[8][16 * 64];    // per-wave [q=li][k-local], swizzled

  const u16* kbase = k + bh * N_ * DH_;
  const u16* vbase = vT + bh * DH_ * N_;

  const int srow_off = l >> 3;          // 0..7
  const int sg = l & 7;                 // dest granule
  const int r0 = w * 8;
  auto stageK = [&](int buf, int kj0) {
    const int row = r0 + srow_off;
    const int gp = sg ^ (row & 7);
    gload_lds16(kbase + (size_t)(kj0 + row) * DH_ + gp * 8, &Kt[buf][r0 * 64]);
  };
  auto stageV = [&](int buf, int kj0) {
    const int row = r0 + srow_off;
    const int gp = sg ^ (row & 7);
    gload_lds16(vbase + (size_t)row * N_ + kj0 + gp * 8, &Vt[buf][r0 * 64]);
  };

  const u16* qp = q + (bh * N_ + qw) * DH_;
  const bf16x8 bq0 = ld_frag(qp + li * DH_ + grp * 8);
  const bf16x8 bq1 = ld_frag(qp + li * DH_ + 32 + grp * 8);

  f32x4 accO[4] = {};            // O^T: d = t2*16+grp*4+j, q = li
  float m = -INFINITY, lsum = 0.f;

  u16* Pw = &P[w][0];
  const int sw = (li & 7) << 3;
  const int prow = li * 64;
  const u16* mrow = mp + bh * (N_ / 16) * N_ + qw + li;

  stageK(0, 0); stageV(0, 0);
  __syncthreads();
  int cur = 0;

  for (int kj0 = 0; kj0 < N_; kj0 += 64) {
    if (kj0 + 64 < N_) { stageK(cur ^ 1, kj0 + 64); stageV(cur ^ 1, kj0 + 64); }
    unsigned mword[4];
#pragma unroll
    for (int t = 0; t < 4; ++t) mword[t] = mrow[(size_t)((kj0 >> 4) + t) * N_];

    f32x4 s[4];
    __builtin_amdgcn_s_setprio(1);
#pragma unroll
    for (int t = 0; t < 4; ++t) {
      const int row = t * 16 + li;
      const int rs = row & 7;
      const bf16x8 ka0 = ld_frag(&Kt[cur][row * 64 + ((grp ^ rs) * 8)]);
      const bf16x8 ka1 = ld_frag(&Kt[cur][row * 64 + (((grp + 4) ^ rs) * 8)]);
      f32x4 z = {0.f, 0.f, 0.f, 0.f};
      z = __builtin_amdgcn_mfma_f32_16x16x32_bf16(ka0, bq0, z, 0, 0, 0);
      z = __builtin_amdgcn_mfma_f32_16x16x32_bf16(ka1, bq1, z, 0, 0, 0);
      s[t] = z;
    }
    __builtin_amdgcn_s_setprio(0);

    // mask (scores already base-2-scaled via Q); lane holds 16 for q = li
    float sv[16];
#pragma unroll
    for (int t = 0; t < 4; ++t) {
      const unsigned mb = (mword[t] >> (grp * 4)) & 0xFu;
#pragma unroll
      for (int j = 0; j < 4; ++j)
        sv[t * 4 + j] = ((mb >> j) & 1u) ? -INFINITY : s[t][j];
    }
    // max3-fusable reduction tree
    const float a0 = fmaxf(fmaxf(sv[0], sv[1]), sv[2]);
    const float a1 = fmaxf(fmaxf(sv[3], sv[4]), sv[5]);
    const float a2 = fmaxf(fmaxf(sv[6], sv[7]), sv[8]);
    const float a3 = fmaxf(fmaxf(sv[9], sv[10]), sv[11]);
    const float a4 = fmaxf(fmaxf(sv[12], sv[13]), sv[14]);
    float rmax = fmaxf(fmaxf(fmaxf(a0, a1), fmaxf(a2, a3)), fmaxf(a4, sv[15]));
    rmax = fmaxf(rmax, __shfl_xor(rmax, 16));
    rmax = fmaxf(rmax, __shfl_xor(rmax, 32));
    // defer-max (threshold in base-2 units)
    if (!__all(rmax <= m + THR2)) {
      const float mnew = fmaxf(m, rmax);
      const float scal = (m == -INFINITY) ? 0.f : exp2f(m - mnew);
      lsum *= scal;
#pragma unroll
      for (int t2 = 0; t2 < 4; ++t2) accO[t2] *= scal;
      m = mnew;
    }
    const float msafe = (m == -INFINITY) ? 0.f : m;
    float psum = 0.f;
    float pv[16];
#pragma unroll
    for (int i = 0; i < 16; ++i) {
      const float e = exp2f(sv[i] - msafe);  // exp2(-inf)=0 zeroes masked
      pv[i] = e;
      psum += e;
    }
    psum += __shfl_xor(psum, 16);
    psum += __shfl_xor(psum, 32);
    lsum += psum;
    // P -> LDS (bf16 via paired cvt_pk), swizzled
#pragma unroll
    for (int t = 0; t < 4; ++t) {
      bf16x2 plo = { (__bf16)pv[t * 4 + 0], (__bf16)pv[t * 4 + 1] };
      bf16x2 phi = { (__bf16)pv[t * 4 + 2], (__bf16)pv[t * 4 + 3] };
      uint2 pk;
      pk.x = __builtin_bit_cast(unsigned, plo);
      pk.y = __builtin_bit_cast(unsigned, phi);
      *(uint2*)&Pw[prow + ((t * 16 + grp * 4) ^ sw)] = pk;
    }
    // PV: O^T[d][q] += V^T[d][k] * P^T[k][q]
    __builtin_amdgcn_s_setprio(1);
#pragma unroll
    for (int kc = 0; kc < 2; ++kc) {
      const bf16x8 pb = ld_frag(&Pw[prow + ((kc * 32 + grp * 8) ^ sw)]);
#pragma unroll
      for (int t2 = 0; t2 < 4; ++t2) {
        const int row = t2 * 16 + li;
        const bf16x8 va = ld_frag(&Vt[cur][row * 64 + (((kc * 4 + grp) ^ (row & 7)) * 8)]);
        accO[t2] = __builtin_amdgcn_mfma_f32_16x16x32_bf16(va, pb, accO[t2], 0, 0, 0);
      }
    }
    __builtin_amdgcn_s_setprio(0);
    __syncthreads();
    cur ^= 1;
  }
  const float inv = (lsum > 0.f) ? 1.0f / lsum : 0.f;  // all-masked row -> 0
  u16* op = outp + ((size_t)b * N_ + qw + li) * D_ + h * DH_;
#pragma unroll
  for (int t2 = 0; t2 < 4; ++t2) {
    bf16x2 o01 = { (__bf16)(accO[t2][0] * inv), (__bf16)(accO[t2][1] * inv) };
    bf16x2 o23 = { (__bf16)(accO[t2][2] * inv), (__bf16)(accO[t2][3] * inv) };
    uint2 ov;
    ov.x = __builtin_bit_cast(unsigned, o01);
    ov.y = __builtin_bit_cast(unsigned, o23);
    *(uint2*)&op[t2 * 16 + grp * 4] = ov;
  }
}

// ---------------------------------------------------------------------------
// Row LayerNorm over bf16 input: ONE WAVE PER ROW, vectorized loads (12
// contiguous bf16/lane, 3x 8B), pure-shuffle reduction (no LDS, no barrier).
// Block = 256 (4 waves = 4 rows); grid = 2048.
// OUTF32=0: write bf16 ybf; OUTF32=1: write fp32 yf.
template<int OUTF32>
__global__ __launch_bounds__(256)
void ln_kernel(const u16* __restrict__ x, const float* __restrict__ g,
               const float* __restrict__ be, u16* __restrict__ ybf,
               float* __restrict__ yf) {
  const int w = threadIdx.x >> 6, lane = threadIdx.x & 63;
  const int row = blockIdx.x * 4 + w;
  const u16* xr = x + (size_t)row * D_ + lane * 12;
  u16x4 p0 = *(const u16x4*)(xr);
  u16x4 p1 = *(const u16x4*)(xr + 4);
  u16x4 p2 = *(const u16x4*)(xr + 8);
  float v[12];
#pragma unroll
  for (int i = 0; i < 4; ++i) {
    v[i] = b2f(p0[i]); v[4 + i] = b2f(p1[i]); v[8 + i] = b2f(p2[i]);
  }
  float s = 0.f, s2 = 0.f;
#pragma unroll
  for (int i = 0; i < 12; ++i) { s += v[i]; s2 += v[i] * v[i]; }
#pragma unroll
  for (int d = 1; d < 64; d <<= 1) { s += __shfl_xor(s, d); s2 += __shfl_xor(s2, d); }
  const float mu = s * (1.0f / D_);
  const float var = fmaxf(s2 * (1.0f / D_) - mu * mu, 0.0f);
  const float rstd = rsqrtf(var + 1e-5f);
  const float* gp = g + lane * 12;
  const float* bp = be + lane * 12;
  float o[12];
#pragma unroll
  for (int c = 0; c < 3; ++c) {
    float4 gv = *(const float4*)(gp + c * 4);
    float4 bv = *(const float4*)(bp + c * 4);
    o[c * 4 + 0] = (v[c * 4 + 0] - mu) * rstd * gv.x + bv.x;
    o[c * 4 + 1] = (v[c * 4 + 1] - mu) * rstd * gv.y + bv.y;
    o[c * 4 + 2] = (v[c * 4 + 2] - mu) * rstd * gv.z + bv.z;
    o[c * 4 + 3] = (v[c * 4 + 3] - mu) * rstd * gv.w + bv.w;
  }
  if constexpr (OUTF32) {
    float* yr = yf + (size_t)row * D_ + lane * 12;
#pragma unroll
    for (int c = 0; c < 3; ++c) {
      float4 ov = { o[c * 4], o[c * 4 + 1], o[c * 4 + 2], o[c * 4 + 3] };
      *(float4*)(yr + c * 4) = ov;
    }
  } else {
    u16* yr = ybf + (size_t)row * D_ + lane * 12;
#pragma unroll
    for (int c = 0; c < 3; ++c) {
      u16x4 ov;
      ov[0] = f2bu(o[c * 4 + 0]); ov[1] = f2bu(o[c * 4 + 1]);
      ov[2] = f2bu(o[c * 4 + 2]); ov[3] = f2bu(o[c * 4 + 3]);
      *(u16x4*)(yr + c * 4) = ov;
    }
  }
}

// ---------------------------------------------------------------------------
extern "C" void kernel_launch(void* const* d_in, const int* in_sizes, int n_in,
                              void* d_out, int out_size, void* d_ws, size_t ws_size,
                              hipStream_t stream) {
  (void)in_sizes; (void)n_in; (void)out_size; (void)ws_size;
  const float* nodes = (const float*)d_in[0];
  const float* rel   = (const float*)d_in[1];
  const int*   nmask = (const int*)d_in[2];
  const float* Wq = (const float*)d_in[3];
  const float* bq = (const float*)d_in[4];
  const float* Wk = (const float*)d_in[5];
  const float* bk = (const float*)d_in[6];
  const float* Wv = (const float*)d_in[7];
  const float* bv = (const float*)d_in[8];
  const float* Wo = (const float*)d_in[9];
  const float* bo = (const float*)d_in[10];
  const float* ln1g = (const float*)d_in[11];
  const float* ln1b = (const float*)d_in[12];
  const float* W1 = (const float*)d_in[13];
  const float* b1 = (const float*)d_in[14];
  const float* W2 = (const float*)d_in[15];
  const float* b2 = (const float*)d_in[16];
  const float* ln2g = (const float*)d_in[17];
  const float* ln2b = (const float*)d_in[18];
  float* out = (float*)d_out;

  char* ws = (char*)d_ws;
  u16* Wqk_bf = (u16*)(ws + 0);          // [Wq;Wk] 1536x768
  u16* Wv_bf  = (u16*)(ws + 2359296);
  u16* Wo_bf  = (u16*)(ws + 3538944);
  u16* W1_bf  = (u16*)(ws + 4718592);
  u16* W2_bf  = (u16*)(ws + 7077888);
  u16* Xbf    = (u16*)(ws + 9437184);    // nodes bf16; stays live (Wo residual)
  u16* qb     = (u16*)(ws + 22020096);   // (b,h,i,dh)
  u16* kb     = (u16*)(ws + 34603008);
  u16* vTb    = (u16*)(ws + 47185920);   // (b,h,dh,i)
  u16* mwb    = (u16*)(ws + 59768832);   // packed mask words; later reused as f1
  u16* prehb  = (u16*)(ws + 22020096);   // bf16, overlays dead qb
  u16* hbf    = (u16*)(ws + 47185920);   // overlays dead vT
  u16* f1b    = (u16*)(ws + 59768832);   // overlays dead mask
  u16* preob  = (u16*)(ws + 84934656);   // bf16
  u16* attno  = (u16*)(ws + 100663296);  // attn output (own buffer; Xbf live)

  const dim3 blk(256);
  // mask packing + all converts in ONE launch
  CvtArgs ca;
  ca.src[0] = Wq; ca.src[1] = Wk; ca.src[2] = Wv; ca.src[3] = Wo;
  ca.src[4] = W1; ca.src[5] = W2; ca.src[6] = nodes;
  ca.dst[0] = Wqk_bf; ca.dst[1] = Wqk_bf + 768 * 768; ca.dst[2] = Wv_bf;
  ca.dst[3] = Wo_bf; ca.dst[4] = W1_bf; ca.dst[5] = W2_bf; ca.dst[6] = Xbf;
  ca.n4[0] = ca.n4[1] = ca.n4[2] = ca.n4[3] = 147456;
  ca.n4[4] = ca.n4[5] = 294912; ca.n4[6] = 1572864;
  ca.start[0] = 2048; ca.start[1] = 2624; ca.start[2] = 3200; ca.start[3] = 3776;
  ca.start[4] = 4352; ca.start[5] = 5504; ca.start[6] = 6656; ca.start[7] = 12800;
  prep_all<<<12800, blk, 0, stream>>>(ca, rel, nmask, mwb);
  // fused Q,K projection + V projection (independent) in ONE launch
  gemm_qkv<<<1152, blk, 0, stream>>>(Xbf, Wqk_bf, Wv_bf, bq, bk, bv, qb, kb, vTb);
  // attention (1D XCD-chunked grid, 512 threads)
  attn<<<768, dim3(512), 0, stream>>>(qb, kb, vTb, mwb, attno);
  // out-proj + bf16 residual(Xbf = nodes) -> bf16 pre_h
  gemm_bt<4><<<dim3(6, 64), blk, 0, stream>>>(attno, Wo_bf, bo, Xbf,
                                              prehb, 768, 768);
  // LN1 -> bf16 h
  ln_kernel<0><<<2048, blk, 0, stream>>>(prehb, ln1g, ln1b, hbf, nullptr);
  // FFN1 + gelu -> bf16
  gemm_bt<3><<<dim3(12, 64), blk, 0, stream>>>(hbf, W1_bf, b1, nullptr,
                                               f1b, 1536, 768);
  // FFN2 + bf16 residual(h) -> bf16 pre_out
  gemm_bt<4><<<dim3(6, 64), blk, 0, stream>>>(f1b, W2_bf, b2, hbf,
                                              preob, 768, 1536);
  // LN2 -> fp32 output
  ln_kernel<1><<<2048, blk, 0, stream>>>(preob, ln2g, ln2b, nullptr, out);
}